// Round 1
// baseline (272.296 us; speedup 1.0000x reference)
//
#include <hip/hip_runtime.h>

using f16   = _Float16;
using f16x4 = __attribute__((ext_vector_type(4))) _Float16;
using f16x8 = __attribute__((ext_vector_type(8))) _Float16;
using f32x4 = __attribute__((ext_vector_type(4))) float;

#define DEVI __device__ __forceinline__

namespace {
constexpr int R_X  = 0;       // 16KB staged input; later P0 @0, P1 @8192
constexpr int R_Q  = 16384;   // Q f16 [64][128]; later O
constexpr int R_K  = 32768;   // K f16 [64][128]; later P2 @32768, P3 @40960
constexpr int R_VT = 49152;   // V^T f16 [128][64]
constexpr float LOGIT_MAX_C = 4.6051701859880914f;  // log(100)
constexpr float L2E = 1.4426950408889634f;
}

// XOR swizzle: breaks the 16-way bank conflict of stride-256B / stride-128B
// row-major tiles on ds_read_b128 (guide §6 G4). Applied on BOTH write & read.
DEVI int swzA(int row, int b) { return (row << 8) + (b ^ ((row & 7) << 4)); }  // 256B rows
DEVI int swzB(int row, int b) { return (row << 7) + (b ^ ((row & 7) << 4)); }  // 128B rows

// Stage one 64x128 fp32 window tile -> f16 swizzled LDS tile (coalesced float4)
DEVI void stage_in(const float* __restrict__ src, char* __restrict__ dst, int tid) {
#pragma unroll
  for (int i = 0; i < 8; ++i) {
    int f = tid + (i << 8);          // float4 index 0..2047
    int row = f >> 5;                // 64 rows of 128 floats
    float4 v = reinterpret_cast<const float4*>(src)[f];
    f16x4 h;
    h[0] = (f16)v.x; h[1] = (f16)v.y; h[2] = (f16)v.z; h[3] = (f16)v.w;
    *reinterpret_cast<f16x4*>(dst + swzA(row, (f & 31) << 3)) = h;
  }
}

DEVI f16x8 ldA(const char* base, int row, int k0) {   // [*, 128] f16 tile
  return *reinterpret_cast<const f16x8*>(base + swzA(row, k0 << 1));
}
DEVI f16x8 ldB(const char* base, int row, int k0) {   // [*, 64] f16 tile
  return *reinterpret_cast<const f16x8*>(base + swzB(row, k0 << 1));
}
// Weight B-fragment straight from global fp32 (L2-resident), convert in-flight
DEVI f16x8 ldW(const float* __restrict__ W, int n, int k0) {
  const float4* p = reinterpret_cast<const float4*>(W + n * 128 + k0);
  float4 a = p[0], c = p[1];
  f16x8 r;
  r[0] = (f16)a.x; r[1] = (f16)a.y; r[2] = (f16)a.z; r[3] = (f16)a.w;
  r[4] = (f16)c.x; r[5] = (f16)c.y; r[6] = (f16)c.z; r[7] = (f16)c.w;
  return r;
}

// out[64, 32w..32w+32) = X(lds) @ W^T (+bias).  MODE 0: dst is [64][128] swzA.
// MODE 1: dst is V^T [128][64] swzB (rows = feature, cols = seq).
template <int MODE>
DEVI void proj_gemm(const char* __restrict__ xb, const float* __restrict__ W,
                    const float* __restrict__ bias, char* __restrict__ dst,
                    int w, int lr, int lg) {
  f16x8 bf[2][4];
#pragma unroll
  for (int n = 0; n < 2; ++n)
#pragma unroll
    for (int kt = 0; kt < 4; ++kt)
      bf[n][kt] = ldW(W, w * 32 + n * 16 + lr, kt * 32 + lg * 8);
  f32x4 acc[4][2];
#pragma unroll
  for (int mt = 0; mt < 4; ++mt)
#pragma unroll
    for (int n = 0; n < 2; ++n)
      acc[mt][n] = f32x4{0.f, 0.f, 0.f, 0.f};
#pragma unroll
  for (int mt = 0; mt < 4; ++mt)
#pragma unroll
    for (int kt = 0; kt < 4; ++kt) {
      f16x8 a = ldA(xb, mt * 16 + lr, kt * 32 + lg * 8);
      acc[mt][0] = __builtin_amdgcn_mfma_f32_16x16x32_f16(a, bf[0][kt], acc[mt][0], 0, 0, 0);
      acc[mt][1] = __builtin_amdgcn_mfma_f32_16x16x32_f16(a, bf[1][kt], acc[mt][1], 0, 0, 0);
    }
  float b0 = bias ? bias[w * 32 + lr] : 0.f;
  float b1 = bias ? bias[w * 32 + 16 + lr] : 0.f;
#pragma unroll
  for (int mt = 0; mt < 4; ++mt)
#pragma unroll
    for (int n = 0; n < 2; ++n)
#pragma unroll
      for (int r = 0; r < 4; ++r) {
        int row = mt * 16 + lg * 4 + r;           // C/D layout: col=lane&15, row=(lane>>4)*4+r
        int col = w * 32 + n * 16 + lr;
        float v = acc[mt][n][r] + (n ? b1 : b0);
        if (MODE == 0)
          *reinterpret_cast<f16*>(dst + swzA(row, col << 1)) = (f16)v;
        else
          *reinterpret_cast<f16*>(dst + swzB(col, row << 1)) = (f16)v;
      }
}

__global__ __launch_bounds__(256, 2)
void fpca_kernel(const float* __restrict__ q_in, const float* __restrict__ k_in,
                 const float* __restrict__ v_in, const float* __restrict__ pos_in,
                 const float* __restrict__ Wq, const float* __restrict__ bq,
                 const float* __restrict__ Wk, const float* __restrict__ Wv,
                 const float* __restrict__ bv, const float* __restrict__ Wp,
                 const float* __restrict__ bp, const float* __restrict__ lsc,
                 float* __restrict__ d_x, float* __restrict__ d_attn) {
  __shared__ char smem[65536];
  const int tid = threadIdx.x;
  const int w = tid >> 6;        // wave id == head id
  const int lane = tid & 63;
  const int lr = lane & 15;
  const int lg = lane >> 4;
  const int win = blockIdx.x;    // (b, wh, ww) flattened
  const int b = win >> 8;
  const size_t winOff = (size_t)win << 13;  // *64*128

  // ---- projections (wave w produces exactly head w's Q/K/V columns) ----
  stage_in(q_in + winOff, smem + R_X, tid);
  __syncthreads();
  proj_gemm<0>(smem + R_X, Wq, bq, smem + R_Q, w, lr, lg);
  __syncthreads();
  stage_in(k_in + winOff, smem + R_X, tid);
  __syncthreads();
  proj_gemm<0>(smem + R_X, Wk, nullptr, smem + R_K, w, lr, lg);
  __syncthreads();
  stage_in(v_in + winOff, smem + R_X, tid);
  __syncthreads();
  proj_gemm<1>(smem + R_X, Wv, bv, smem + R_VT, w, lr, lg);
  // no barrier needed: QK^T reads only this wave's own Q/K columns

  // ---- S = Q_h K_h^T  (K dim = 32 = one MFMA step) ----
  f16x8 aQ[4], bK[4];
#pragma unroll
  for (int t = 0; t < 4; ++t) {
    aQ[t] = ldA(smem + R_Q, t * 16 + lr, w * 32 + lg * 8);
    bK[t] = ldA(smem + R_K, t * 16 + lr, w * 32 + lg * 8);
  }
  f32x4 s[4][4];
#pragma unroll
  for (int mt = 0; mt < 4; ++mt)
#pragma unroll
    for (int nt = 0; nt < 4; ++nt)
      s[mt][nt] = f32x4{0.f, 0.f, 0.f, 0.f};
#pragma unroll
  for (int mt = 0; mt < 4; ++mt)
#pragma unroll
    for (int nt = 0; nt < 4; ++nt)
      s[mt][nt] = __builtin_amdgcn_mfma_f32_16x16x32_f16(aQ[mt], bK[nt], s[mt][nt], 0, 0, 0);

  // ---- logits: scale + position bias; softmax over 64 cols ----
  const float scale = exp2f(fminf(lsc[w], LOGIT_MAX_C) * L2E);  // exp(min(ls, log100))
  const float* pos = pos_in + (((size_t)b * 4 + w) << 12);
#pragma unroll
  for (int mt = 0; mt < 4; ++mt)
#pragma unroll
    for (int nt = 0; nt < 4; ++nt)
#pragma unroll
      for (int r = 0; r < 4; ++r) {
        int row = mt * 16 + lg * 4 + r;
        int col = nt * 16 + lr;
        s[mt][nt][r] = s[mt][nt][r] * scale + pos[(row << 6) + col];
      }
  // each row lives on the 16 lanes sharing lg (4 cols each) -> xor-shuffle 1,2,4,8
#pragma unroll
  for (int mt = 0; mt < 4; ++mt)
#pragma unroll
    for (int r = 0; r < 4; ++r) {
      float m = fmaxf(fmaxf(s[mt][0][r], s[mt][1][r]), fmaxf(s[mt][2][r], s[mt][3][r]));
      m = fmaxf(m, __shfl_xor(m, 1));
      m = fmaxf(m, __shfl_xor(m, 2));
      m = fmaxf(m, __shfl_xor(m, 4));
      m = fmaxf(m, __shfl_xor(m, 8));
      float sum = 0.f;
#pragma unroll
      for (int nt = 0; nt < 4; ++nt) {
        float e = exp2f((s[mt][nt][r] - m) * L2E);
        s[mt][nt][r] = e;
        sum += e;
      }
      sum += __shfl_xor(sum, 1);
      sum += __shfl_xor(sum, 2);
      sum += __shfl_xor(sum, 4);
      sum += __shfl_xor(sum, 8);
      float rinv = __builtin_amdgcn_rcpf(sum);
#pragma unroll
      for (int nt = 0; nt < 4; ++nt) s[mt][nt][r] *= rinv;
    }

  __syncthreads();  // all Q/K/X LDS reads done -> P (over X,K) and O (over Q) writable

  // ---- write attn (fp32, output 1) and P (f16 LDS, wave-private buffer) ----
  char* Pb = smem + (w < 2 ? w * 8192 : R_K + (w - 2) * 8192);
  float* attn_out = d_attn + (((size_t)win * 4 + w) << 12);
#pragma unroll
  for (int mt = 0; mt < 4; ++mt)
#pragma unroll
    for (int nt = 0; nt < 4; ++nt)
#pragma unroll
      for (int r = 0; r < 4; ++r) {
        int row = mt * 16 + lg * 4 + r;
        int col = nt * 16 + lr;
        float p = s[mt][nt][r];
        attn_out[(row << 6) + col] = p;
        *reinterpret_cast<f16*>(Pb + swzB(row, col << 1)) = (f16)p;
      }

  // ---- O_h = P @ V_h  (B-operand from V^T: contiguous 16B reads) ----
  f16x8 bV[2][2];
#pragma unroll
  for (int n = 0; n < 2; ++n)
#pragma unroll
    for (int kt = 0; kt < 2; ++kt)
      bV[n][kt] = ldB(smem + R_VT, w * 32 + n * 16 + lr, kt * 32 + lg * 8);
  f32x4 oacc[4][2];
#pragma unroll
  for (int mt = 0; mt < 4; ++mt)
#pragma unroll
    for (int n = 0; n < 2; ++n)
      oacc[mt][n] = f32x4{0.f, 0.f, 0.f, 0.f};
#pragma unroll
  for (int mt = 0; mt < 4; ++mt)
#pragma unroll
    for (int kt = 0; kt < 2; ++kt) {
      f16x8 aP = ldB(Pb, mt * 16 + lr, kt * 32 + lg * 8);
      oacc[mt][0] = __builtin_amdgcn_mfma_f32_16x16x32_f16(aP, bV[0][kt], oacc[mt][0], 0, 0, 0);
      oacc[mt][1] = __builtin_amdgcn_mfma_f32_16x16x32_f16(aP, bV[1][kt], oacc[mt][1], 0, 0, 0);
    }
  // O (merged heads) -> R_Q region, wave-private columns
#pragma unroll
  for (int mt = 0; mt < 4; ++mt)
#pragma unroll
    for (int n = 0; n < 2; ++n)
#pragma unroll
      for (int r = 0; r < 4; ++r) {
        int row = mt * 16 + lg * 4 + r;
        int col = w * 32 + n * 16 + lr;
        *reinterpret_cast<f16*>(smem + R_Q + swzA(row, col << 1)) = (f16)oacc[mt][n][r];
      }
  __syncthreads();

  // ---- x = O @ Wp^T + bp -> global fp32 (output 0) ----
  f16x8 bf[2][4];
#pragma unroll
  for (int n = 0; n < 2; ++n)
#pragma unroll
    for (int kt = 0; kt < 4; ++kt)
      bf[n][kt] = ldW(Wp, w * 32 + n * 16 + lr, kt * 32 + lg * 8);
  f32x4 xacc[4][2];
#pragma unroll
  for (int mt = 0; mt < 4; ++mt)
#pragma unroll
    for (int n = 0; n < 2; ++n)
      xacc[mt][n] = f32x4{0.f, 0.f, 0.f, 0.f};
#pragma unroll
  for (int mt = 0; mt < 4; ++mt)
#pragma unroll
    for (int kt = 0; kt < 4; ++kt) {
      f16x8 a = ldA(smem + R_Q, mt * 16 + lr, kt * 32 + lg * 8);
      xacc[mt][0] = __builtin_amdgcn_mfma_f32_16x16x32_f16(a, bf[0][kt], xacc[mt][0], 0, 0, 0);
      xacc[mt][1] = __builtin_amdgcn_mfma_f32_16x16x32_f16(a, bf[1][kt], xacc[mt][1], 0, 0, 0);
    }
  const float b0 = bp[w * 32 + lr];
  const float b1 = bp[w * 32 + 16 + lr];
  float* xo = d_x + winOff;
#pragma unroll
  for (int mt = 0; mt < 4; ++mt)
#pragma unroll
    for (int n = 0; n < 2; ++n)
#pragma unroll
      for (int r = 0; r < 4; ++r) {
        int row = mt * 16 + lg * 4 + r;
        int col = w * 32 + n * 16 + lr;
        xo[(row << 7) + col] = xacc[mt][n][r] + (n ? b1 : b0);
      }
}

extern "C" void kernel_launch(void* const* d_in, const int* in_sizes, int n_in,
                              void* d_out, int out_size, void* d_ws, size_t ws_size,
                              hipStream_t stream) {
  const float* q   = (const float*)d_in[0];
  const float* k   = (const float*)d_in[1];
  const float* v   = (const float*)d_in[2];
  const float* pos = (const float*)d_in[3];
  const float* Wq  = (const float*)d_in[4];
  const float* bq  = (const float*)d_in[5];
  const float* Wk  = (const float*)d_in[6];
  const float* Wv  = (const float*)d_in[7];
  const float* bv  = (const float*)d_in[8];
  const float* Wp  = (const float*)d_in[9];
  const float* bp  = (const float*)d_in[10];
  const float* ls  = (const float*)d_in[11];
  float* d_x    = (float*)d_out;
  float* d_attn = d_x + (size_t)16 * 16 * 16 * 64 * 128;  // 33,554,432
  fpca_kernel<<<4096, 256, 0, stream>>>(q, k, v, pos, Wq, bq, Wk, Wv, bv, Wp,
                                        bp, ls, d_x, d_attn);
}